// Round 17
// baseline (51.459 us; speedup 1.0000x reference)
//
#include <hip/hip_runtime.h>

// VectorQuantiser R17: issue-count attack. 32x32x16 MFMA (half the MFMA instrs)
// + e2 folded INTO the MFMA (A=ones @k0,k1; B=f16-split of -e2/2) so the
// accumulator holds s = dot - e2/2 directly -> argmax update = 3 VALU/dist
// (was 4) and no e2 fmaf/loads. Keeps R10's proven shell: 1024 blocks x 256thr
// (4 waves x 32 rows), 16 chunks x 32 codes, T14 reg-staged es dbuf (2x8KB),
// pre-swizzled contiguous ecvt (4-bit XOR for the 32-code pattern), in-wave
// argmin reduce, gather-free epilogue. LDS ~25KB.
// argmin dist == argmax s; first-occurrence preserved (strict >, ascending codes).

typedef _Float16 f16;
typedef _Float16 f16x8  __attribute__((ext_vector_type(8)));
typedef float    f32x4  __attribute__((ext_vector_type(4)));
typedef float    f32x16 __attribute__((ext_vector_type(16)));

#define NELEM0 8388608
#define FLTMAX 3.402823466e38f
// ws: [0,131072) ecvt_sw f16[512][128] (4-bit-XOR pre-swizzled);
//     [131072,139264) e2q f16[512][8] = {-e2h/2, -e2l/2, 0...};
//     [139264,270336) embt f32[512][64] affine pre-applied
#define WS_NEED 270336

// prep: 8 blocks x 256 thr; block owns 64 codes; thread quarter q owns 16 d's.
__global__ void prep_kernel(const float* __restrict__ emb, const float* __restrict__ meanp,
                            const float* __restrict__ sdp, f16* __restrict__ ecvt,
                            f16* __restrict__ e2q, float* __restrict__ embt) {
    __shared__ float e2part[4][64];
    const int tid  = threadIdx.x;
    const int code = blockIdx.x * 64 + (tid & 63);
    const int q    = tid >> 6;                       // d quarter
    const float mean = meanp[0];
    const float sd   = sdp[0];
    float s = 0.0f;
    #pragma unroll
    for (int j = 0; j < 16; ++j) {
        const int d = q * 16 + j;
        float v = emb[d * 512 + code];               // coalesced across codes
        s = fmaf(v, v, s);
        f16 h = (f16)v;
        f16 l = (f16)(v - (float)h);
        const int sh = (d >> 3) ^ (code & 15);       // hi slot (logical 0-7)
        const int sl = ((d >> 3) + 8) ^ (code & 15); // lo slot (logical 8-15)
        ecvt[code * 128 + sh * 8 + (d & 7)] = h;
        ecvt[code * 128 + sl * 8 + (d & 7)] = l;
        embt[code * 64 + d] = (v + mean) * sd;       // affine pre-applied
    }
    e2part[q][tid & 63] = s;
    __syncthreads();
    if (q == 0) {
        const int c_ = tid & 63;
        float e2 = ((e2part[0][c_] + e2part[1][c_]) + e2part[2][c_]) + e2part[3][c_];
        float t  = -0.5f * e2;
        f16 th = (f16)t;
        f16 tl = (f16)(t - (float)th);
        f16* dst = e2q + code * 8;
        dst[0] = th; dst[1] = tl;
        #pragma unroll
        for (int e = 2; e < 8; ++e) dst[e] = (f16)0.0f;
    }
}

__global__ __launch_bounds__(256, 4)
void vq_main(const float* __restrict__ x, const float* __restrict__ meanp,
             const float* __restrict__ sdp, const f16* __restrict__ ecvt,
             const f16* __restrict__ e2q, const float* __restrict__ embt,
             float* __restrict__ out, float* __restrict__ outIdx)
{
    __shared__ __align__(16) f16 es[2][4096];        // 2 x 8 KB (32-code chunks)
    __shared__ __align__(16) f16 e2s[4096];          // 8 KB: e2q copy
    __shared__ int kbs[128];

    const int tid  = threadIdx.x;
    const int lane = tid & 63;
    const int wid  = tid >> 6;       // 0..3; wave owns 32 rows
    const int lrow = lane & 31;      // MFMA row (A) / col (B) index
    const int kh   = lane >> 5;      // k-half selector

    const int blk   = blockIdx.x;    // 1024 = 32 b x 16 g x 2 chalf
    const int chalf = blk & 1;
    const int g     = (blk >> 1) & 15;
    const int b     = blk >> 5;

    const float sd   = sdp[0];
    const bool  sdz  = (sd == 0.0f);
    const float sinv = sdz ? 0.0f : (1.0f / sd);
    const float mean = meanp[0];

    const size_t xslab = (size_t)b * 262144 + (size_t)g * 16384;
    const int c0 = chalf * 128 + wid * 32;           // wave's first row (global c)

    // ---- A fragments: rows = c0 + lrow; d = p*16 + kh*8 + e ----
    f16x8 axh[4], axl[4];
    {
        const float* rp = x + xslab + c0 + lrow;
        #pragma unroll
        for (int p = 0; p < 4; ++p)
            #pragma unroll
            for (int e = 0; e < 8; ++e) {
                const int d = p * 16 + kh * 8 + e;
                float v  = rp[d * 256];
                float sv = fmaf(v, sinv, -mean);
                f16 h = (f16)sv;
                axh[p][e] = h;
                axl[p][e] = (f16)(sv - (float)h);
            }
    }
    f16x8 aone;
    #pragma unroll
    for (int e = 0; e < 8; ++e)
        aone[e] = (kh == 0 && e < 2) ? (f16)1.0f : (f16)0.0f;

    // ---- stage e2s (8KB) + es chunk 0 (8KB), contiguous ----
    #pragma unroll
    for (int i = 0; i < 2; ++i)
        *reinterpret_cast<f16x8*>(&e2s[(i * 256 + tid) * 8]) =
            *reinterpret_cast<const f16x8*>(&e2q[(i * 256 + tid) * 8]);
    f16x8 pre0 = *reinterpret_cast<const f16x8*>(&ecvt[tid * 8]);
    f16x8 pre1 = *reinterpret_cast<const f16x8*>(&ecvt[2048 + tid * 8]);
    *reinterpret_cast<f16x8*>(&es[0][tid * 8])        = pre0;
    *reinterpret_cast<f16x8*>(&es[0][2048 + tid * 8]) = pre1;
    __syncthreads();

    float bestv[16];
    int   besti[16];
    #pragma unroll
    for (int r = 0; r < 16; ++r) { bestv[r] = -FLTMAX; besti[r] = 0; }

    // ---- main loop: 16 chunks x 32 codes ----
    for (int ch = 0; ch < 16; ++ch) {
        const int cur = ch & 1;
        const f16* eb = &es[cur][0];

        if (ch < 15) {                               // T14: issue next-chunk EARLY
            pre0 = *reinterpret_cast<const f16x8*>(&ecvt[(ch + 1) * 4096 + tid * 8]);
            pre1 = *reinterpret_cast<const f16x8*>(&ecvt[(ch + 1) * 4096 + 2048 + tid * 8]);
        }

        f32x16 acc = (f32x16){0.f,0.f,0.f,0.f, 0.f,0.f,0.f,0.f,
                              0.f,0.f,0.f,0.f, 0.f,0.f,0.f,0.f};
        {   // e2 term: s starts at -e2/2
            const f16x8 be2 = *reinterpret_cast<const f16x8*>(&e2s[(ch * 32 + lrow) * 8]);
            acc = __builtin_amdgcn_mfma_f32_32x32x16_f16(aone, be2, acc, 0, 0, 0);
        }
        #pragma unroll
        for (int p = 0; p < 4; ++p) {                // xh.eh + xl.eh
            const f16x8 bp = *reinterpret_cast<const f16x8*>(
                &eb[lrow * 128 + (((p * 2 + kh) ^ (lrow & 15)) << 3)]);
            acc = __builtin_amdgcn_mfma_f32_32x32x16_f16(axh[p], bp, acc, 0, 0, 0);
            acc = __builtin_amdgcn_mfma_f32_32x32x16_f16(axl[p], bp, acc, 0, 0, 0);
        }
        #pragma unroll
        for (int p = 0; p < 4; ++p) {                // xh.el
            const f16x8 bp = *reinterpret_cast<const f16x8*>(
                &eb[lrow * 128 + ((((p * 2 + kh) + 8) ^ (lrow & 15)) << 3)]);
            acc = __builtin_amdgcn_mfma_f32_32x32x16_f16(axh[p], bp, acc, 0, 0, 0);
        }

        const int codeg = ch * 32 + lrow;
        #pragma unroll
        for (int r = 0; r < 16; ++r) {               // 3 VALU per dist
            if (acc[r] > bestv[r]) { bestv[r] = acc[r]; besti[r] = codeg; }
        }

        if (ch < 15) {                               // T14: write-late
            *reinterpret_cast<f16x8*>(&es[cur ^ 1][tid * 8])        = pre0;
            *reinterpret_cast<f16x8*>(&es[cur ^ 1][2048 + tid * 8]) = pre1;
        }
        __syncthreads();
    }

    // ---- argmax reduce across the 32 codes held by this lane-half ----
    #pragma unroll
    for (int r = 0; r < 16; ++r) {
        float v = bestv[r]; int i = besti[r];
        #pragma unroll
        for (int m = 1; m < 32; m <<= 1) {
            float v2 = __shfl_xor(v, m, 64);
            int   i2 = __shfl_xor(i, m, 64);
            if (v2 > v || (v2 == v && i2 < i)) { v = v2; i = i2; }
        }
        bestv[r] = v; besti[r] = i;
    }
    if (lrow == 0) {                                  // lanes 0 and 32
        #pragma unroll
        for (int r = 0; r < 16; ++r) {
            const int row = (r & 3) + 8 * (r >> 2) + 4 * kh;   // C/D row map
            kbs[wid * 32 + row] = besti[r];
        }
    }
    __syncthreads();

    // ---- epilogue: stream embt row, coalesced d-major stores ----
    {
        const int c_ = tid & 127;
        const int dh = tid >> 7;                     // d half (32 each)
        const int k  = kbs[c_];
        const float* qrow = embt + k * 64 + dh * 32; // L2-resident
        float* op = out + xslab + (size_t)(dh * 32) * 256 + chalf * 128 + c_;
        #pragma unroll
        for (int q4 = 0; q4 < 8; ++q4) {
            f32x4 qq = *reinterpret_cast<const f32x4*>(&qrow[q4 * 4]);
            #pragma unroll
            for (int j = 0; j < 4; ++j)
                op[(q4 * 4 + j) * 256] = qq[j];
        }
    }
    if (tid < 128)
        outIdx[(size_t)(b * 256 + chalf * 128 + tid) * 16 + g] = (float)kbs[tid];
}

// ---------------- fallback (ws too small): R5-style self-contained -------------
__device__ __forceinline__ int swz(int row, int koff) {
    return row * 128 + (koff ^ ((row & 7) << 3));
}

__global__ __launch_bounds__(512, 2)
void vq_fallback(const float* __restrict__ x, const float* __restrict__ meanp,
                 const float* __restrict__ sdp, const float* __restrict__ emb,
                 float* __restrict__ out, float* __restrict__ outIdx)
{
    __shared__ __align__(16) f16 xa[128 * 128];
    __shared__ __align__(16) f16 es2[128 * 128];
    __shared__ float e2s[512];
    __shared__ float red_v[4][128];
    __shared__ int   red_i[4][128];
    __shared__ int   kb[128];

    const int tid  = threadIdx.x;
    const int lane = tid & 63;
    const int wid  = tid >> 6;
    const int wr   = wid >> 2;
    const int wc   = wid & 3;
    const int lr   = lane & 15;
    const int lk   = lane >> 4;

    const int blk   = blockIdx.x;
    const int chalf = blk & 1;
    const int g     = (blk >> 1) & 15;
    const int b     = blk >> 5;

    const float mean = meanp[0];
    const float sd   = sdp[0];
    const bool  sdz  = (sd == 0.0f);
    const float safe = sdz ? 1.0f : sd;

    const int xbase = b * 262144 + g * 16384 + chalf * 128;

    {
        const int c_ = tid & 127;
        const int dq = tid >> 7;
        const float* src = x + xbase + c_;
        #pragma unroll
        for (int jv = 0; jv < 2; ++jv) {
            f16x8 hi, lo;
            #pragma unroll
            for (int e = 0; e < 8; ++e) {
                int d = dq * 16 + jv * 8 + e;
                float v = src[d * 256];
                float s = (sdz ? 0.0f : v / safe) - mean;
                f16 h = (f16)s;
                hi[e] = h;
                lo[e] = (f16)(s - (float)h);
            }
            *reinterpret_cast<f16x8*>(&xa[swz(c_, dq * 16 + jv * 8)])      = hi;
            *reinterpret_cast<f16x8*>(&xa[swz(c_, 64 + dq * 16 + jv * 8)]) = lo;
        }
    }
    {
        float s = 0.0f;
        for (int d = 0; d < 64; ++d) {
            float v = emb[d * 512 + tid];
            s = fmaf(v, v, s);
        }
        e2s[tid] = s;
    }

    float bestv[16];
    int   besti[16];
    #pragma unroll
    for (int s = 0; s < 16; ++s) { bestv[s] = FLTMAX; besti[s] = 0; }

    for (int ch = 0; ch < 4; ++ch) {
        __syncthreads();
        {
            const int cl = tid & 127;
            const int dq = tid >> 7;
            const float* srcE = emb + ch * 128 + cl;
            #pragma unroll
            for (int jv = 0; jv < 2; ++jv) {
                f16x8 hi, lo;
                #pragma unroll
                for (int e = 0; e < 8; ++e) {
                    int d = dq * 16 + jv * 8 + e;
                    float v = srcE[d * 512];
                    f16 h = (f16)v;
                    hi[e] = h;
                    lo[e] = (f16)(v - (float)h);
                }
                *reinterpret_cast<f16x8*>(&es2[swz(cl, dq * 16 + jv * 8)])      = hi;
                *reinterpret_cast<f16x8*>(&es2[swz(cl, 64 + dq * 16 + jv * 8)]) = lo;
            }
        }
        __syncthreads();

        f32x4 acc[4][2];
        #pragma unroll
        for (int fi = 0; fi < 4; ++fi)
            #pragma unroll
            for (int fj = 0; fj < 2; ++fj)
                acc[fi][fj] = (f32x4){0.f, 0.f, 0.f, 0.f};

        #pragma unroll
        for (int t = 0; t < 3; ++t) {
            const int ah2 = (t == 2) ? 1 : 0;
            const int eh2 = (t == 1) ? 1 : 0;
            #pragma unroll
            for (int dh2 = 0; dh2 < 2; ++dh2) {
                const int kB = eh2 * 64 + dh2 * 32 + lk * 8;
                const int kA = ah2 * 64 + dh2 * 32 + lk * 8;
                f16x8 bf[2], af[4];
                #pragma unroll
                for (int fj = 0; fj < 2; ++fj)
                    bf[fj] = *reinterpret_cast<const f16x8*>(
                        &es2[swz(wc * 32 + fj * 16 + lr, kB)]);
                #pragma unroll
                for (int fi = 0; fi < 4; ++fi)
                    af[fi] = *reinterpret_cast<const f16x8*>(
                        &xa[swz(wr * 64 + fi * 16 + lr, kA)]);
                #pragma unroll
                for (int fi = 0; fi < 4; ++fi)
                    #pragma unroll
                    for (int fj = 0; fj < 2; ++fj)
                        acc[fi][fj] = __builtin_amdgcn_mfma_f32_16x16x32_f16(
                            af[fi], bf[fj], acc[fi][fj], 0, 0, 0);
            }
        }

        #pragma unroll
        for (int fj = 0; fj < 2; ++fj) {
            const int codeg = ch * 128 + wc * 32 + fj * 16 + lr;
            const float e2v = e2s[codeg];
            #pragma unroll
            for (int fi = 0; fi < 4; ++fi)
                #pragma unroll
                for (int r = 0; r < 4; ++r) {
                    float vd = fmaf(-2.0f, acc[fi][fj][r], e2v);
                    const int s = fi * 4 + r;
                    if (vd < bestv[s]) { bestv[s] = vd; besti[s] = codeg; }
                }
        }
    }

    #pragma unroll
    for (int s = 0; s < 16; ++s) {
        float v = bestv[s]; int i = besti[s];
        #pragma unroll
        for (int m = 1; m < 16; m <<= 1) {
            float v2 = __shfl_xor(v, m, 64);
            int   i2 = __shfl_xor(i, m, 64);
            if (v2 < v || (v2 == v && i2 < i)) { v = v2; i = i2; }
        }
        bestv[s] = v; besti[s] = i;
    }
    if (lr == 0) {
        #pragma unroll
        for (int fi = 0; fi < 4; ++fi)
            #pragma unroll
            for (int r = 0; r < 4; ++r) {
                int row = wr * 64 + fi * 16 + lk * 4 + r;
                red_v[wc][row] = bestv[fi * 4 + r];
                red_i[wc][row] = besti[fi * 4 + r];
            }
    }
    __syncthreads();
    if (tid < 128) {
        float bv = red_v[0][tid]; int bi = red_i[0][tid];
        #pragma unroll
        for (int w2 = 1; w2 < 4; ++w2) {
            float v = red_v[w2][tid]; int i = red_i[w2][tid];
            if (v < bv || (v == bv && i < bi)) { bv = v; bi = i; }
        }
        kb[tid] = bi;
    }
    __syncthreads();

    float* out_ = out + xbase;
    #pragma unroll 4
    for (int i = 0; i < 16; ++i) {
        int lin = i * 512 + tid;
        int c_  = lin & 127;
        int d   = lin >> 7;
        float q = emb[d * 512 + kb[c_]];
        out_[d * 256 + c_] = (q + mean) * sd;
    }
    if (tid < 128) {
        int n = (b * 256 + chalf * 128 + tid) * 16 + g;
        outIdx[n] = (float)kb[tid];
    }
}

extern "C" void kernel_launch(void* const* d_in, const int* in_sizes, int n_in,
                              void* d_out, int out_size, void* d_ws, size_t ws_size,
                              hipStream_t stream) {
    const float* x    = (const float*)d_in[0];
    const float* mean = (const float*)d_in[1];
    const float* sd   = (const float*)d_in[2];
    const float* emb  = (const float*)d_in[3];
    float* out    = (float*)d_out;
    float* outIdx = out + NELEM0;

    if (ws_size >= (size_t)WS_NEED) {
        f16*   ecvt = (f16*)d_ws;
        f16*   e2q  = (f16*)((char*)d_ws + 131072);
        float* embt = (float*)((char*)d_ws + 139264);
        prep_kernel<<<dim3(8), dim3(256), 0, stream>>>(emb, mean, sd, ecvt, e2q, embt);
        vq_main<<<dim3(1024), dim3(256), 0, stream>>>(x, mean, sd, ecvt, e2q, embt, out, outIdx);
    } else {
        vq_fallback<<<dim3(1024), dim3(512), 0, stream>>>(x, mean, sd, emb, out, outIdx);
    }
}